// Round 9
// baseline (513.973 us; speedup 1.0000x reference)
//
#include <hip/hip_runtime.h>

#define IN_F 256
#define OUT_F 64
#define BLK1 512          // blocks in coarse passes (P1/P2)
#define BKT 128           // nodes per bucket

typedef __attribute__((ext_vector_type(8))) short s16x8;
typedef __attribute__((ext_vector_type(4))) float f32x4;

__device__ __forceinline__ unsigned short bf16_rne(float f) {
    unsigned u = __builtin_bit_cast(unsigned, f);
    u += 0x7FFFu + ((u >> 16) & 1u);
    return (unsigned short)(u >> 16);
}
__device__ __forceinline__ float bf16_f(unsigned short u) {
    return __builtin_bit_cast(float, ((unsigned)u) << 16);
}

// ---------------------------------------------------------------------------
// P1: per-block coarse-bucket histograms (bucket = node>>7) for dst AND src,
// via LDS atomics. cnt layout (bucket-major): dst -> [b*BLK1+blk],
// src -> [(nb+b)*BLK1+blk]. No global atomics anywhere.
// ---------------------------------------------------------------------------
__global__ __launch_bounds__(256) void k_coarse(const int* __restrict__ src,
                                                const int* __restrict__ dst,
                                                int* __restrict__ cnt,
                                                int nb, int ne) {
    __shared__ int hD[1024], hS[1024];
    const int blk = blockIdx.x, tid = threadIdx.x;
    for (int i = tid; i < 1024; i += 256) { hD[i] = 0; hS[i] = 0; }
    __syncthreads();
    const int epb = (ne + BLK1 - 1) / BLK1;
    const int e0 = blk * epb, e1 = min(ne, e0 + epb);
    for (int e = e0 + tid; e < e1; e += 256) {
        atomicAdd(&hD[dst[e] >> 7], 1);
        atomicAdd(&hS[src[e] >> 7], 1);
    }
    __syncthreads();
    for (int bb = tid; bb < nb; bb += 256) {
        cnt[bb * BLK1 + blk] = hD[bb];
        cnt[(nb + bb) * BLK1 + blk] = hS[bb];
    }
}

// ---------------------------------------------------------------------------
// Exclusive scan over m = 2*nb*BLK1 elements. Final per-element partial add
// folded into consumers (cnt[idx] + partials[idx>>10]).
// ---------------------------------------------------------------------------
__global__ __launch_bounds__(256) void k_scan1(const int* __restrict__ deg,
                                               int* __restrict__ excl,
                                               int* __restrict__ partials, int m) {
    __shared__ int sd[256];
    const int tid = threadIdx.x;
    const int idx = blockIdx.x * 1024 + tid * 4;
    int v0 = 0, v1 = 0, v2 = 0, v3 = 0;
    if (idx     < m) v0 = deg[idx];
    if (idx + 1 < m) v1 = deg[idx + 1];
    if (idx + 2 < m) v2 = deg[idx + 2];
    if (idx + 3 < m) v3 = deg[idx + 3];
    const int tsum = v0 + v1 + v2 + v3;
    sd[tid] = tsum;
    __syncthreads();
    for (int off = 1; off < 256; off <<= 1) {
        int t = (tid >= off) ? sd[tid - off] : 0;
        __syncthreads();
        sd[tid] += t;
        __syncthreads();
    }
    const int texcl = sd[tid] - tsum;
    if (tid == 255) partials[blockIdx.x] = sd[255];
    if (idx     < m) excl[idx]     = texcl;
    if (idx + 1 < m) excl[idx + 1] = texcl + v0;
    if (idx + 2 < m) excl[idx + 2] = texcl + v0 + v1;
    if (idx + 3 < m) excl[idx + 3] = texcl + v0 + v1 + v2;
}

__global__ __launch_bounds__(1024) void k_scan2(int* __restrict__ partials, int nb) {
    __shared__ int sd[1024];
    const int tid = threadIdx.x;
    const int v = (tid < nb) ? partials[tid] : 0;
    sd[tid] = v;
    __syncthreads();
    for (int off = 1; off < 1024; off <<= 1) {
        int t = (tid >= off) ? sd[tid - off] : 0;
        __syncthreads();
        sd[tid] += t;
        __syncthreads();
    }
    if (tid < nb) partials[tid] = sd[tid] - v;  // exclusive
}

// ---------------------------------------------------------------------------
// P2: partition edges into coarse buckets via LDS cursors.
// dst entry: (dst&127)<<17 | src (24 bits); src entry: src&127.
// dst entries land in tmp[0,ne), src entries in tmp[ne,2ne) by construction.
// ---------------------------------------------------------------------------
__global__ __launch_bounds__(256) void k_part(const int* __restrict__ src,
                                              const int* __restrict__ dst,
                                              const int* __restrict__ cnt,
                                              const int* __restrict__ partials,
                                              unsigned* __restrict__ tmp,
                                              int nb, int ne) {
    __shared__ int cD[1024], cS[1024];
    const int blk = blockIdx.x, tid = threadIdx.x;
    for (int bb = tid; bb < nb; bb += 256) {
        int iD = bb * BLK1 + blk;
        int iS = (nb + bb) * BLK1 + blk;
        cD[bb] = cnt[iD] + partials[iD >> 10];
        cS[bb] = cnt[iS] + partials[iS >> 10];
    }
    __syncthreads();
    const int epb = (ne + BLK1 - 1) / BLK1;
    const int e0 = blk * epb, e1 = min(ne, e0 + epb);
    for (int e = e0 + tid; e < e1; e += 256) {
        int d = dst[e], s = src[e];
        int pD = atomicAdd(&cD[d >> 7], 1);
        tmp[pD] = ((unsigned)(d & 127) << 17) | (unsigned)s;
        int pS = atomicAdd(&cS[s >> 7], 1);
        tmp[pS] = (unsigned)(s & 127);
    }
}

// ---------------------------------------------------------------------------
// P3-src: one block per bucket. LDS histogram of src entries -> deg_out.
// ---------------------------------------------------------------------------
__global__ __launch_bounds__(256) void k_fine_src(const int* __restrict__ cnt,
                                                  const int* __restrict__ partials,
                                                  const unsigned* __restrict__ tmp,
                                                  int* __restrict__ deg_out,
                                                  int n, int nb, int ne) {
    __shared__ int hist[BKT];
    const int b = blockIdx.x, tid = threadIdx.x;
    const int ib = (nb + b) * BLK1;
    const int base = cnt[ib] + partials[ib >> 10];
    const int ie = (nb + b + 1) * BLK1;
    const int end = (b + 1 < nb) ? (cnt[ie] + partials[ie >> 10]) : 2 * ne;
    if (tid < BKT) hist[tid] = 0;
    __syncthreads();
    for (int i = base + tid; i < end; i += 256)
        atomicAdd(&hist[tmp[i] & 127u], 1);
    __syncthreads();
    const int node = b * BKT + tid;
    if (tid < BKT && node < n) deg_out[node] = hist[tid];
}

// ---------------------------------------------------------------------------
// GEMM: h(bf16) = diag(rsqrt(max(deg_out,1))) * X * W, 16x16x32 bf16 MFMA.
// A-fragments straight from global, scaled+converted in-register; W^T (32 KB
// bf16, XOR-swizzled) in LDS, staged once per block, 2 row-tiles of 64.
// ---------------------------------------------------------------------------
__global__ __launch_bounds__(256, 4) void k_gemm(const float* __restrict__ x,
                                                 const float* __restrict__ W,
                                                 const int* __restrict__ deg_out,
                                                 unsigned short* __restrict__ h, int n) {
    __shared__ char lds[32768];
    const int tid = threadIdx.x;
    const int lane = tid & 63;
    const int wid = tid >> 6;

    {
        const int f = tid & 63;
        const int kg = (tid >> 6) * 64;
        const int swz = (f & 7) << 4;
#pragma unroll
        for (int j = 0; j < 16; ++j) {
            const int k0 = kg + j * 4;
            unsigned u0 = bf16_rne(W[(k0 + 0) * OUT_F + f]);
            unsigned u1 = bf16_rne(W[(k0 + 1) * OUT_F + f]);
            unsigned u2 = bf16_rne(W[(k0 + 2) * OUT_F + f]);
            unsigned u3 = bf16_rne(W[(k0 + 3) * OUT_F + f]);
            uint2 p;
            p.x = u0 | (u1 << 16);
            p.y = u2 | (u3 << 16);
            int byte = f * 512 + ((k0 * 2) ^ swz);
            *(uint2*)(lds + byte) = p;
        }
    }
    __syncthreads();

    const int r15 = lane & 15;           // A row within 16 / B col within 16
    const int q = lane >> 4;             // k-quarter
    const int bswz = (r15 & 7) << 4;
    const int b_base = r15 * 512;
    const int rq = q * 4;

#pragma unroll
    for (int p = 0; p < 2; ++p) {
        const int row = blockIdx.x * 128 + p * 64 + wid * 16 + r15;
        const int rowc = min(row, n - 1);                  // clamp (stores guarded)
        const float s = rsqrtf(fmaxf((float)deg_out[rowc], 1.0f));
        const float* xr = x + (size_t)rowc * IN_F + q * 8;

        f32x4 acc0 = {0.f, 0.f, 0.f, 0.f};
        f32x4 acc1 = acc0, acc2 = acc0, acc3 = acc0;

#pragma unroll
        for (int kk = 0; kk < 8; ++kk) {
            float4 a0 = *(const float4*)(xr + kk * 32);
            float4 a1 = *(const float4*)(xr + kk * 32 + 4);
            s16x8 a;
            a[0] = (short)bf16_rne(a0.x * s);
            a[1] = (short)bf16_rne(a0.y * s);
            a[2] = (short)bf16_rne(a0.z * s);
            a[3] = (short)bf16_rne(a0.w * s);
            a[4] = (short)bf16_rne(a1.x * s);
            a[5] = (short)bf16_rne(a1.y * s);
            a[6] = (short)bf16_rne(a1.z * s);
            a[7] = (short)bf16_rne(a1.w * s);
            const int off = (q * 16 + kk * 64) ^ bswz;     // XOR in bits 4-6: carry-free
            s16x8 b0 = *(const s16x8*)(lds + b_base + off);
            s16x8 b1 = *(const s16x8*)(lds + b_base + 8192 + off);
            s16x8 b2 = *(const s16x8*)(lds + b_base + 16384 + off);
            s16x8 b3 = *(const s16x8*)(lds + b_base + 24576 + off);
            acc0 = __builtin_amdgcn_mfma_f32_16x16x32_bf16(a, b0, acc0, 0, 0, 0);
            acc1 = __builtin_amdgcn_mfma_f32_16x16x32_bf16(a, b1, acc1, 0, 0, 0);
            acc2 = __builtin_amdgcn_mfma_f32_16x16x32_bf16(a, b2, acc2, 0, 0, 0);
            acc3 = __builtin_amdgcn_mfma_f32_16x16x32_bf16(a, b3, acc3, 0, 0, 0);
        }

        // D layout: row=(lane>>4)*4+j, col=lane&15 (m89-verified)
#pragma unroll
        for (int j = 0; j < 4; ++j) {
            const int grow = blockIdx.x * 128 + p * 64 + wid * 16 + rq + j;
            if (grow < n) {
                unsigned short* hp = h + (size_t)grow * OUT_F + r15;
                hp[0]  = bf16_rne(acc0[j]);
                hp[16] = bf16_rne(acc1[j]);
                hp[32] = bf16_rne(acc2[j]);
                hp[48] = bf16_rne(acc3[j]);
            }
        }
    }
}

// ---------------------------------------------------------------------------
// Fused aggregation: one block per dst bucket (128 nodes). 32 KB LDS f32
// accumulator; per edge one wave gathers h[src]'s 128 B row (lane=feat) and
// ds_add_f32's into acc[d&127][feat] (bank = f%32, 2-way alias = free).
// Degree histogram rides along (lane 0). Epilogue: out = acc*rsqrt(deg)+b.
// No fine sort, no src_sorted round-trip, no global atomics.
// ---------------------------------------------------------------------------
__global__ __launch_bounds__(512) void k_agg_fused(const int* __restrict__ cnt,
                                                   const int* __restrict__ partials,
                                                   const unsigned* __restrict__ tmp,
                                                   const unsigned short* __restrict__ h,
                                                   const float* __restrict__ b,
                                                   float* __restrict__ out,
                                                   int n, int nb, int ne) {
    __shared__ float acc[BKT * OUT_F];   // 32 KB
    __shared__ int hist[BKT];
    const int bidx = blockIdx.x, tid = threadIdx.x;
    const int ib = bidx * BLK1;
    const int base = cnt[ib] + partials[ib >> 10];
    const int ie = (bidx + 1) * BLK1;
    const int end = (bidx + 1 < nb) ? (cnt[ie] + partials[ie >> 10]) : ne;

    for (int i = tid; i < BKT * OUT_F; i += 512) acc[i] = 0.f;
    if (tid < BKT) hist[tid] = 0;
    __syncthreads();

    const int wid = tid >> 6, lane = tid & 63;
    for (int i = base + wid * 2; i < end; i += 16) {   // 8 waves x 2 edges
        unsigned v0 = tmp[i];
        const bool p1 = (i + 1 < end);
        unsigned v1 = p1 ? tmp[i + 1] : v0;
        const int s0 = v0 & 0x1FFFFu, d0 = v0 >> 17;
        const int s1 = v1 & 0x1FFFFu, d1 = v1 >> 17;
        float f0 = bf16_f(h[(size_t)s0 * OUT_F + lane]);   // 2 independent chains
        float f1 = bf16_f(h[(size_t)s1 * OUT_F + lane]);
        if (lane == 0) atomicAdd(&hist[d0], 1);
        atomicAdd(&acc[d0 * OUT_F + lane], f0);
        if (p1) {
            if (lane == 0) atomicAdd(&hist[d1], 1);
            atomicAdd(&acc[d1 * OUT_F + lane], f1);
        }
    }
    __syncthreads();

    for (int j = tid; j < BKT * OUT_F; j += 512) {
        const int ln = j >> 6;
        const int node = bidx * BKT + ln;
        if (node < n) {
            const float scale = rsqrtf(fmaxf((float)hist[ln], 1.0f));
            out[(size_t)node * OUT_F + (j & 63)] = acc[j] * scale + b[j & 63];
        }
    }
}

extern "C" void kernel_launch(void* const* d_in, const int* in_sizes, int n_in,
                              void* d_out, int out_size, void* d_ws, size_t ws_size,
                              hipStream_t stream) {
    const float* x   = (const float*)d_in[0];
    const int*   src = (const int*)d_in[1];
    const int*   dst = (const int*)d_in[2];
    const float* W   = (const float*)d_in[3];
    const float* b   = (const float*)d_in[4];
    float* out = (float*)d_out;

    const int n  = in_sizes[0] / IN_F;   // 100000
    const int ne = in_sizes[1];          // 1000000

    const int nb = (n + BKT - 1) / BKT;  // 782 buckets (<= 1024)
    const int m  = 2 * nb * BLK1;        // cnt matrix size (800768)

    int* cnt        = (int*)d_ws;                 // m
    int* partials   = cnt + m;                    // 1024
    unsigned* tmp   = (unsigned*)(partials + 1024);// 2*ne
    int* deg_out    = (int*)(tmp + 2 * (size_t)ne); // n
    unsigned short* h = (unsigned short*)(deg_out + n);  // n*64 bf16

    const int nb_scan = (m + 1023) / 1024;        // 782 (<= 1024)

    k_coarse<<<BLK1, 256, 0, stream>>>(src, dst, cnt, nb, ne);
    k_scan1<<<nb_scan, 256, 0, stream>>>(cnt, cnt, partials, m);
    k_scan2<<<1, 1024, 0, stream>>>(partials, nb_scan);
    k_part<<<BLK1, 256, 0, stream>>>(src, dst, cnt, partials, tmp, nb, ne);
    k_fine_src<<<nb, 256, 0, stream>>>(cnt, partials, tmp, deg_out, n, nb, ne);
    k_gemm<<<(n + 127) / 128, 256, 0, stream>>>(x, W, deg_out, h, n);
    k_agg_fused<<<nb, 512, 0, stream>>>(cnt, partials, tmp, h, b, out, n, nb, ne);
}

// Round 10
// 118.048 us; speedup vs baseline: 4.3539x; 4.3539x over previous
//
#include <hip/hip_runtime.h>

#define IN_F 256
#define OUT_F 64
#define BLK1 512          // blocks in coarse passes (P1/P2)
#define BKT 128           // nodes per bucket
#define CAP 4096          // LDS edge-list capacity (bucket mean 1280, sigma~36)

typedef __attribute__((ext_vector_type(8))) short s16x8;
typedef __attribute__((ext_vector_type(4))) float f32x4;
typedef __attribute__((ext_vector_type(4))) unsigned u32x4;

__device__ __forceinline__ unsigned short bf16_rne(float f) {
    unsigned u = __builtin_bit_cast(unsigned, f);
    u += 0x7FFFu + ((u >> 16) & 1u);
    return (unsigned short)(u >> 16);
}
__device__ __forceinline__ float bf16_lo(unsigned u) {
    return __builtin_bit_cast(float, u << 16);
}
__device__ __forceinline__ float bf16_hi(unsigned u) {
    return __builtin_bit_cast(float, u & 0xFFFF0000u);
}
// packed f32x2 -> bf16x2 (RNE), single VALU op
__device__ __forceinline__ unsigned pk2(float a, float b) {
    unsigned r;
    asm("v_cvt_pk_bf16_f32 %0, %1, %2" : "=v"(r) : "v"(a), "v"(b));
    return r;
}

// ---------------------------------------------------------------------------
// P1: per-block coarse-bucket histograms (bucket = node>>7) for dst AND src.
// ---------------------------------------------------------------------------
__global__ __launch_bounds__(256) void k_coarse(const int* __restrict__ src,
                                                const int* __restrict__ dst,
                                                int* __restrict__ cnt,
                                                int nb, int ne) {
    __shared__ int hD[1024], hS[1024];
    const int blk = blockIdx.x, tid = threadIdx.x;
    for (int i = tid; i < 1024; i += 256) { hD[i] = 0; hS[i] = 0; }
    __syncthreads();
    const int epb = (ne + BLK1 - 1) / BLK1;
    const int e0 = blk * epb, e1 = min(ne, e0 + epb);
    for (int e = e0 + tid; e < e1; e += 256) {
        atomicAdd(&hD[dst[e] >> 7], 1);
        atomicAdd(&hS[src[e] >> 7], 1);
    }
    __syncthreads();
    for (int bb = tid; bb < nb; bb += 256) {
        cnt[bb * BLK1 + blk] = hD[bb];
        cnt[(nb + bb) * BLK1 + blk] = hS[bb];
    }
}

// ---------------------------------------------------------------------------
// Exclusive scan over m = 2*nb*BLK1 elements; partial add folded into consumers.
// ---------------------------------------------------------------------------
__global__ __launch_bounds__(256) void k_scan1(const int* __restrict__ deg,
                                               int* __restrict__ excl,
                                               int* __restrict__ partials, int m) {
    __shared__ int sd[256];
    const int tid = threadIdx.x;
    const int idx = blockIdx.x * 1024 + tid * 4;
    int v0 = 0, v1 = 0, v2 = 0, v3 = 0;
    if (idx     < m) v0 = deg[idx];
    if (idx + 1 < m) v1 = deg[idx + 1];
    if (idx + 2 < m) v2 = deg[idx + 2];
    if (idx + 3 < m) v3 = deg[idx + 3];
    const int tsum = v0 + v1 + v2 + v3;
    sd[tid] = tsum;
    __syncthreads();
    for (int off = 1; off < 256; off <<= 1) {
        int t = (tid >= off) ? sd[tid - off] : 0;
        __syncthreads();
        sd[tid] += t;
        __syncthreads();
    }
    const int texcl = sd[tid] - tsum;
    if (tid == 255) partials[blockIdx.x] = sd[255];
    if (idx     < m) excl[idx]     = texcl;
    if (idx + 1 < m) excl[idx + 1] = texcl + v0;
    if (idx + 2 < m) excl[idx + 2] = texcl + v0 + v1;
    if (idx + 3 < m) excl[idx + 3] = texcl + v0 + v1 + v2;
}

__global__ __launch_bounds__(1024) void k_scan2(int* __restrict__ partials, int nb) {
    __shared__ int sd[1024];
    const int tid = threadIdx.x;
    const int v = (tid < nb) ? partials[tid] : 0;
    sd[tid] = v;
    __syncthreads();
    for (int off = 1; off < 1024; off <<= 1) {
        int t = (tid >= off) ? sd[tid - off] : 0;
        __syncthreads();
        sd[tid] += t;
        __syncthreads();
    }
    if (tid < nb) partials[tid] = sd[tid] - v;  // exclusive
}

// ---------------------------------------------------------------------------
// P2: partition edges into coarse buckets via LDS cursors.
// dst entry: (dst&127)<<17 | src; src entry: src&127.
// ---------------------------------------------------------------------------
__global__ __launch_bounds__(256) void k_part(const int* __restrict__ src,
                                              const int* __restrict__ dst,
                                              const int* __restrict__ cnt,
                                              const int* __restrict__ partials,
                                              unsigned* __restrict__ tmp,
                                              int nb, int ne) {
    __shared__ int cD[1024], cS[1024];
    const int blk = blockIdx.x, tid = threadIdx.x;
    for (int bb = tid; bb < nb; bb += 256) {
        int iD = bb * BLK1 + blk;
        int iS = (nb + bb) * BLK1 + blk;
        cD[bb] = cnt[iD] + partials[iD >> 10];
        cS[bb] = cnt[iS] + partials[iS >> 10];
    }
    __syncthreads();
    const int epb = (ne + BLK1 - 1) / BLK1;
    const int e0 = blk * epb, e1 = min(ne, e0 + epb);
    for (int e = e0 + tid; e < e1; e += 256) {
        int d = dst[e], s = src[e];
        int pD = atomicAdd(&cD[d >> 7], 1);
        tmp[pD] = ((unsigned)(d & 127) << 17) | (unsigned)s;
        int pS = atomicAdd(&cS[s >> 7], 1);
        tmp[pS] = (unsigned)(s & 127);
    }
}

// ---------------------------------------------------------------------------
// P3-src: one block per bucket. LDS histogram of src entries -> deg_out.
// ---------------------------------------------------------------------------
__global__ __launch_bounds__(256) void k_fine_src(const int* __restrict__ cnt,
                                                  const int* __restrict__ partials,
                                                  const unsigned* __restrict__ tmp,
                                                  int* __restrict__ deg_out,
                                                  int n, int nb, int ne) {
    __shared__ int hist[BKT];
    const int b = blockIdx.x, tid = threadIdx.x;
    const int ib = (nb + b) * BLK1;
    const int base = cnt[ib] + partials[ib >> 10];
    const int ie = (nb + b + 1) * BLK1;
    const int end = (b + 1 < nb) ? (cnt[ie] + partials[ie >> 10]) : 2 * ne;
    if (tid < BKT) hist[tid] = 0;
    __syncthreads();
    for (int i = base + tid; i < end; i += 256)
        atomicAdd(&hist[tmp[i] & 127u], 1);
    __syncthreads();
    const int node = b * BKT + tid;
    if (tid < BKT && node < n) deg_out[node] = hist[tid];
}

// ---------------------------------------------------------------------------
// GEMM v3: h(bf16) = (X @ W) * rsqrt(max(deg_out,1)) row-scale at OUTPUT.
// A-fragments from global, v_cvt_pk_bf16_f32 conversion (2 elems/op);
// W^T (32 KB bf16, XOR-swizzled) in LDS; 2 row-tiles of 64 per block.
// ---------------------------------------------------------------------------
__global__ __launch_bounds__(256, 4) void k_gemm(const float* __restrict__ x,
                                                 const float* __restrict__ W,
                                                 const int* __restrict__ deg_out,
                                                 unsigned short* __restrict__ h, int n) {
    __shared__ char lds[32768];
    const int tid = threadIdx.x;
    const int lane = tid & 63;
    const int wid = tid >> 6;

    {
        const int f = tid & 63;
        const int kg = (tid >> 6) * 64;
        const int swz = (f & 7) << 4;
#pragma unroll
        for (int j = 0; j < 16; ++j) {
            const int k0 = kg + j * 4;
            float w0 = W[(k0 + 0) * OUT_F + f];
            float w1 = W[(k0 + 1) * OUT_F + f];
            float w2 = W[(k0 + 2) * OUT_F + f];
            float w3 = W[(k0 + 3) * OUT_F + f];
            uint2 p;
            p.x = pk2(w0, w1);
            p.y = pk2(w2, w3);
            *(uint2*)(lds + f * 512 + ((k0 * 2) ^ swz)) = p;
        }
    }
    __syncthreads();

    const int r15 = lane & 15;           // A row within 16 / B col within 16
    const int q = lane >> 4;             // k-quarter
    const int bswz = (r15 & 7) << 4;
    const int b_base = r15 * 512;
    const int rq = q * 4;

#pragma unroll
    for (int p = 0; p < 2; ++p) {
        const int row = blockIdx.x * 128 + p * 64 + wid * 16 + r15;
        const int rowc = min(row, n - 1);                  // clamp (stores guarded)
        const float* xr = x + (size_t)rowc * IN_F + q * 8;

        f32x4 acc0 = {0.f, 0.f, 0.f, 0.f};
        f32x4 acc1 = acc0, acc2 = acc0, acc3 = acc0;

#pragma unroll
        for (int kk = 0; kk < 8; ++kk) {
            float4 a0 = *(const float4*)(xr + kk * 32);
            float4 a1 = *(const float4*)(xr + kk * 32 + 4);
            u32x4 au;
            au[0] = pk2(a0.x, a0.y);
            au[1] = pk2(a0.z, a0.w);
            au[2] = pk2(a1.x, a1.y);
            au[3] = pk2(a1.z, a1.w);
            s16x8 a = __builtin_bit_cast(s16x8, au);
            const int off = (q * 16 + kk * 64) ^ bswz;     // XOR in bits 4-6: carry-free
            s16x8 b0 = *(const s16x8*)(lds + b_base + off);
            s16x8 b1 = *(const s16x8*)(lds + b_base + 8192 + off);
            s16x8 b2 = *(const s16x8*)(lds + b_base + 16384 + off);
            s16x8 b3 = *(const s16x8*)(lds + b_base + 24576 + off);
            acc0 = __builtin_amdgcn_mfma_f32_16x16x32_bf16(a, b0, acc0, 0, 0, 0);
            acc1 = __builtin_amdgcn_mfma_f32_16x16x32_bf16(a, b1, acc1, 0, 0, 0);
            acc2 = __builtin_amdgcn_mfma_f32_16x16x32_bf16(a, b2, acc2, 0, 0, 0);
            acc3 = __builtin_amdgcn_mfma_f32_16x16x32_bf16(a, b3, acc3, 0, 0, 0);
        }

        // D layout: row=(lane>>4)*4+j, col=lane&15 (m89-verified); scale at output
#pragma unroll
        for (int j = 0; j < 4; ++j) {
            const int grow = blockIdx.x * 128 + p * 64 + wid * 16 + rq + j;
            if (grow < n) {
                const float s = rsqrtf(fmaxf((float)deg_out[grow], 1.0f));
                unsigned short* hp = h + (size_t)grow * OUT_F + r15;
                hp[0]  = bf16_rne(acc0[j] * s);
                hp[16] = bf16_rne(acc1[j] * s);
                hp[32] = bf16_rne(acc2[j] * s);
                hp[48] = bf16_rne(acc3[j] * s);
            }
        }
    }
}

// ---------------------------------------------------------------------------
// Fused fine-sort + aggregate: one 512-thread block per 128-node dst bucket.
// Phase A (as in proven k_fine_dst): LDS hist -> LDS scan -> LDS-cursor
// scatter of src list into eidx[CAP] (int cursor atomics only).
// Phase B: 8 waves, each owns nodes wid, wid+8, ...; walks its node's LDS
// edge sublist, gathers h rows (half-wave dword loads, 2 chains), register
// accumulate, write out*rsqrt(deg)+b. No global atomics, no f32 atomics.
// ---------------------------------------------------------------------------
__global__ __launch_bounds__(512) void k_agg(const int* __restrict__ cnt,
                                             const int* __restrict__ partials,
                                             const unsigned* __restrict__ tmp,
                                             const unsigned* __restrict__ h32,
                                             const float* __restrict__ b,
                                             float* __restrict__ out,
                                             int n, int nb, int ne) {
    __shared__ int hist[BKT], sd[BKT], cur[BKT], stt[BKT];
    __shared__ int eidx[CAP];            // 16 KB
    const int bkt = blockIdx.x, tid = threadIdx.x;
    const int ib = bkt * BLK1;
    const int base = cnt[ib] + partials[ib >> 10];
    const int ie = (bkt + 1) * BLK1;
    const int end = (bkt + 1 < nb) ? (cnt[ie] + partials[ie >> 10]) : ne;

    if (tid < BKT) hist[tid] = 0;
    __syncthreads();
    for (int i = base + tid; i < end; i += 512)
        atomicAdd(&hist[tmp[i] >> 17], 1);
    __syncthreads();
    int dg0 = 0;
    if (tid < BKT) { dg0 = hist[tid]; sd[tid] = dg0; }
    __syncthreads();
    for (int off = 1; off < BKT; off <<= 1) {
        int t = 0;
        if (tid < BKT && tid >= off) t = sd[tid - off];
        __syncthreads();
        if (tid < BKT) sd[tid] += t;
        __syncthreads();
    }
    if (tid < BKT) {
        const int excl = sd[tid] - dg0;
        cur[tid] = excl;
        stt[tid] = excl;
    }
    __syncthreads();
    for (int i = base + tid; i < end; i += 512) {
        unsigned v = tmp[i];
        int pos = atomicAdd(&cur[v >> 17], 1);
        eidx[min(pos, CAP - 1)] = (int)(v & 0x1FFFFu);
    }
    __syncthreads();

    const int wid = tid >> 6, lane = tid & 63;
    const int f2 = lane & 31, half = lane >> 5;
    for (int nd = wid; nd < BKT; nd += 8) {
        const int node = bkt * BKT + nd;
        if (node >= n) continue;
        const int st = stt[nd];
        const int dg = hist[nd];
        float a0 = 0.f, a1 = 0.f, c0 = 0.f, c1 = 0.f;
        int i = 0;
        const int dg4 = dg & ~3;
        for (; i < dg4; i += 4) {
            int s0 = eidx[st + i + half];
            int s1 = eidx[st + i + 2 + half];
            unsigned u0 = h32[s0 * 32 + f2];     // 2 independent chains
            unsigned u1 = h32[s1 * 32 + f2];
            a0 += bf16_lo(u0); a1 += bf16_hi(u0);
            c0 += bf16_lo(u1); c1 += bf16_hi(u1);
        }
        for (; i < dg; i += 2) {                 // predicated tail
            const int e = i + half;
            const bool v = e < dg;
            int s = eidx[st + (v ? e : i)];
            unsigned u = h32[s * 32 + f2];
            if (v) { a0 += bf16_lo(u); a1 += bf16_hi(u); }
        }
        a0 += c0; a1 += c1;
        a0 += __shfl_xor(a0, 32, 64);
        a1 += __shfl_xor(a1, 32, 64);
        if (half == 0) {
            const float scale = rsqrtf(fmaxf((float)dg, 1.0f));
            float2 v;
            v.x = a0 * scale + b[f2 * 2];
            v.y = a1 * scale + b[f2 * 2 + 1];
            *(float2*)&out[(size_t)node * OUT_F + f2 * 2] = v;
        }
    }
}

extern "C" void kernel_launch(void* const* d_in, const int* in_sizes, int n_in,
                              void* d_out, int out_size, void* d_ws, size_t ws_size,
                              hipStream_t stream) {
    const float* x   = (const float*)d_in[0];
    const int*   src = (const int*)d_in[1];
    const int*   dst = (const int*)d_in[2];
    const float* W   = (const float*)d_in[3];
    const float* b   = (const float*)d_in[4];
    float* out = (float*)d_out;

    const int n  = in_sizes[0] / IN_F;   // 100000
    const int ne = in_sizes[1];          // 1000000

    const int nb = (n + BKT - 1) / BKT;  // 782 buckets (<= 1024)
    const int m  = 2 * nb * BLK1;        // cnt matrix size (800768)

    int* cnt        = (int*)d_ws;                  // m
    int* partials   = cnt + m;                     // 1024
    unsigned* tmp   = (unsigned*)(partials + 1024);// 2*ne
    int* deg_out    = (int*)(tmp + 2 * (size_t)ne);// n
    unsigned short* h = (unsigned short*)(deg_out + n);  // n*64 bf16

    const int nb_scan = (m + 1023) / 1024;         // 782 (<= 1024)

    k_coarse<<<BLK1, 256, 0, stream>>>(src, dst, cnt, nb, ne);
    k_scan1<<<nb_scan, 256, 0, stream>>>(cnt, cnt, partials, m);
    k_scan2<<<1, 1024, 0, stream>>>(partials, nb_scan);
    k_part<<<BLK1, 256, 0, stream>>>(src, dst, cnt, partials, tmp, nb, ne);
    k_fine_src<<<nb, 256, 0, stream>>>(cnt, partials, tmp, deg_out, n, nb, ne);
    k_gemm<<<(n + 127) / 128, 256, 0, stream>>>(x, W, deg_out, h, n);
    k_agg<<<nb, 512, 0, stream>>>(cnt, partials, tmp, (const unsigned*)h, b, out, n, nb, ne);
}